// Round 15
// baseline (527.682 us; speedup 1.0000x reference)
//
#include <hip/hip_runtime.h>
#include <hip/hip_fp16.h>

#define N_NODES 50000
#define N_EDGES 800000
#define F_IN 128
#define HID 64
#define N_GRAPHS 64

#define SCAN_B ((N_NODES + 255) / 256)     // 196 blocks
#define FUSE_B ((N_EDGES + 255) / 256)     // 3125 blocks; == N_NODES/16 exactly

// ---------------- degree (int4-vectorized over contiguous dst row) ----------------
__global__ void deg_kernel(const int* __restrict__ ei, int* __restrict__ ideg, int E) {
    int i = blockIdx.x * blockDim.x + threadIdx.x;
    if (i * 4 >= E) return;
    int4 d = ((const int4*)(ei + E))[i];   // dst = ei[1][*], contiguous
    atomicAdd(&ideg[d.x], 1);
    atomicAdd(&ideg[d.y], 1);
    atomicAdd(&ideg[d.z], 1);
    atomicAdd(&ideg[d.w], 1);
}

// ---------------- 3-phase parallel exclusive scan of in-degrees (+ fused dinv) ----------------
__global__ void scan_part(const int* __restrict__ ideg, int* __restrict__ bsum, int n) {
    __shared__ int s[256];
    int t = threadIdx.x;
    int i = blockIdx.x * 256 + t;
    s[t] = (i < n) ? ideg[i] : 0;
    __syncthreads();
    for (int o = 128; o > 0; o >>= 1) {
        if (t < o) s[t] += s[t + o];
        __syncthreads();
    }
    if (t == 0) bsum[blockIdx.x] = s[0];
}

__global__ void scan_base(const int* __restrict__ bsum, int* __restrict__ bbase, int B) {
    __shared__ int s[256];
    int t = threadIdx.x;
    s[t] = (t < B) ? bsum[t] : 0;
    __syncthreads();
    for (int o = 1; o < 256; o <<= 1) {
        int v = (t >= o) ? s[t - o] : 0;
        __syncthreads();
        s[t] += v;
        __syncthreads();
    }
    if (t < B) bbase[t] = (t == 0) ? 0 : s[t - 1];
}

__global__ void scan_final(const int* __restrict__ ideg, const int* __restrict__ bbase,
                           int* __restrict__ offs, int* __restrict__ cur,
                           float* __restrict__ dinv, int n) {
    __shared__ int s[256];
    int t = threadIdx.x;
    int i = blockIdx.x * 256 + t;
    int v = (i < n) ? ideg[i] : 0;
    s[t] = v;
    __syncthreads();
    for (int o = 1; o < 256; o <<= 1) {
        int u = (t >= o) ? s[t - o] : 0;
        __syncthreads();
        s[t] += u;
        __syncthreads();
    }
    int excl = bbase[blockIdx.x] + s[t] - v;   // exclusive prefix
    if (i < n) {
        offs[i] = excl; cur[i] = excl;
        dinv[i] = rsqrtf((float)v + 1.0f);     // fused normalization coeff
    }
    if (i == n - 1) offs[n] = excl + v;        // total == E
}

// ---------------- FUSED (phased): every block fills 256 edges AND matmuls 16 nodes ----------------
// csr entry is 4B packed {w:fp16 hi16, src:u16 lo16} (N_NODES < 2^16).
__global__ void fused_fill_mm1(const int* __restrict__ ei, const float* __restrict__ dinv,
                               int* __restrict__ cur, unsigned int* __restrict__ csr,
                               const float* __restrict__ X, const float* __restrict__ W,
                               __half* __restrict__ Y16, int n, int E) {
    constexpr int F = F_IN;
    constexpr int S = F + 4;
    __shared__ float sWt[64 * S];          // [feat][k]
    __shared__ float sX[16 * F];           // [node][k]
    int tid = threadIdx.x;

    // ---- phase 1: fill front-end (atomic issued now, store deferred) ----
    int e = blockIdx.x * 256 + tid;
    unsigned int pk = 0; int pos = -1;
    if (e < E) {
        int esrc = ei[e];
        int d = ei[E + e];
        __half hw = __float2half(dinv[esrc]);
        pk = ((unsigned int)(*(unsigned short*)&hw) << 16) | (unsigned int)(esrc & 0xFFFF);
        pos = atomicAdd(&cur[d], 1);
    }

    // ---- phase 2: matmul Y[16 nodes, 64] = X @ W ----
    for (int j = tid; j < F * 64; j += 256) {
        int k = j >> 6, f = j & 63;        // W is [k][f] row-major
        sWt[f * S + k] = W[j];
    }
    int nodeBase = blockIdx.x * 16;
    for (int i = tid; i < 16 * F; i += 256) {
        int node = nodeBase + i / F;
        sX[i] = (node < n) ? X[(size_t)node * F + (i % F)] : 0.0f;
    }
    __syncthreads();
    int feat = tid & 63;
    int q = tid >> 6;                      // wave id: nodes q*4 .. q*4+3
    const float4* wt = (const float4*)&sWt[feat * S];
    const float4* x0 = (const float4*)&sX[(q * 4 + 0) * F];
    const float4* x1 = (const float4*)&sX[(q * 4 + 1) * F];
    const float4* x2 = (const float4*)&sX[(q * 4 + 2) * F];
    const float4* x3 = (const float4*)&sX[(q * 4 + 3) * F];
    float a0 = 0.f, a1 = 0.f, a2 = 0.f, a3 = 0.f;
#pragma unroll 8
    for (int k4 = 0; k4 < F / 4; ++k4) {
        float4 w = wt[k4];
        float4 v;
        v = x0[k4]; a0 += v.x * w.x + v.y * w.y + v.z * w.z + v.w * w.w;
        v = x1[k4]; a1 += v.x * w.x + v.y * w.y + v.z * w.z + v.w * w.w;
        v = x2[k4]; a2 += v.x * w.x + v.y * w.y + v.z * w.z + v.w * w.w;
        v = x3[k4]; a3 += v.x * w.x + v.y * w.y + v.z * w.z + v.w * w.w;
    }
    int n0 = nodeBase + q * 4;
    if (n0 + 0 < n) Y16[(size_t)(n0 + 0) * 64 + feat] = __float2half(a0);
    if (n0 + 1 < n) Y16[(size_t)(n0 + 1) * 64 + feat] = __float2half(a1);
    if (n0 + 2 < n) Y16[(size_t)(n0 + 2) * 64 + feat] = __float2half(a2);
    if (n0 + 3 < n) Y16[(size_t)(n0 + 3) * 64 + feat] = __float2half(a3);

    // ---- phase 3: deferred CSR store (4B packed) ----
    if (pos >= 0) csr[pos] = pk;
}

// ---------------- dense matmul (layers 2,3): h fp32 in -> hp16 out ----------------
template <int F>
__global__ void matmul_kernel(const float* __restrict__ X, const float* __restrict__ W,
                              __half* __restrict__ Y16, int n) {
    constexpr int S = F + 4;
    __shared__ float sWt[64 * S];
    __shared__ float sX[16 * F];
    int tid = threadIdx.x;
    for (int j = tid; j < F * 64; j += 256) {
        int k = j >> 6, f = j & 63;
        sWt[f * S + k] = W[j];
    }
    int nodeBase = blockIdx.x * 16;
    for (int i = tid; i < 16 * F; i += 256) {
        int node = nodeBase + i / F;
        sX[i] = (node < n) ? X[(size_t)node * F + (i % F)] : 0.0f;
    }
    __syncthreads();
    int feat = tid & 63;
    int q = tid >> 6;
    const float4* wt = (const float4*)&sWt[feat * S];
    const float4* x0 = (const float4*)&sX[(q * 4 + 0) * F];
    const float4* x1 = (const float4*)&sX[(q * 4 + 1) * F];
    const float4* x2 = (const float4*)&sX[(q * 4 + 2) * F];
    const float4* x3 = (const float4*)&sX[(q * 4 + 3) * F];
    float a0 = 0.f, a1 = 0.f, a2 = 0.f, a3 = 0.f;
#pragma unroll 8
    for (int k4 = 0; k4 < F / 4; ++k4) {
        float4 w = wt[k4];
        float4 v;
        v = x0[k4]; a0 += v.x * w.x + v.y * w.y + v.z * w.z + v.w * w.w;
        v = x1[k4]; a1 += v.x * w.x + v.y * w.y + v.z * w.z + v.w * w.w;
        v = x2[k4]; a2 += v.x * w.x + v.y * w.y + v.z * w.z + v.w * w.w;
        v = x3[k4]; a3 += v.x * w.x + v.y * w.y + v.z * w.z + v.w * w.w;
    }
    int n0 = nodeBase + q * 4;
    if (n0 + 0 < n) Y16[(size_t)(n0 + 0) * 64 + feat] = __float2half(a0);
    if (n0 + 1 < n) Y16[(size_t)(n0 + 1) * 64 + feat] = __float2half(a1);
    if (n0 + 2 < n) Y16[(size_t)(n0 + 2) * 64 + feat] = __float2half(a2);
    if (n0 + 3 < n) Y16[(size_t)(n0 + 3) * 64 + feat] = __float2half(a3);
}

// ---------------- agg v4: 8 row-gathers per dwordx4 VMEM instruction ----------------
// One wave per node. Wave = 8 groups x 8 lanes; group g handles edge i+g, lane sub
// loads uint4 (16B) -> 8 lanes x 16B = the full 128B fp16 row in ONE instruction
// covering 8 distinct rows. Per 8 edges: 2 VMEM instructions. At the L2 line-service
// wall (~16 cyc/line); keep LEAN (R8/R11/R12: attached work regresses).
__global__ void agg_kernel(const __half* __restrict__ hp16, const float* __restrict__ dinv,
                           const int* __restrict__ offs, const unsigned int* __restrict__ csr,
                           const float* __restrict__ b, float* __restrict__ out, int n) {
    int node = blockIdx.x * 4 + (threadIdx.x >> 6);
    if (node >= n) return;
    int lane = threadIdx.x & 63;
    int g = lane >> 3;                     // edge-group 0..7
    int sub = lane & 7;                    // feature octet (feats 8*sub..8*sub+7)
    int beg = offs[node], end = offs[node + 1];

    float a0 = 0.f, a1 = 0.f, a2 = 0.f, a3 = 0.f;
    float a4 = 0.f, a5 = 0.f, a6 = 0.f, a7 = 0.f;
#pragma unroll 2
    for (int i = beg; i < end; i += 8) {
        int idx = i + g;
        unsigned int pk = csr[min(idx, end - 1)];
        int src = (int)(pk & 0xFFFFu);
        __half_raw hr; hr.x = (unsigned short)(pk >> 16);
        float w = (idx < end) ? __half2float(*(__half*)&hr) : 0.f;
        uint4 hv = *(const uint4*)(hp16 + (size_t)src * 64 + sub * 8);
        float2 f01 = __half22float2(*(const __half2*)&hv.x);
        float2 f23 = __half22float2(*(const __half2*)&hv.y);
        float2 f45 = __half22float2(*(const __half2*)&hv.z);
        float2 f67 = __half22float2(*(const __half2*)&hv.w);
        a0 += f01.x * w; a1 += f01.y * w; a2 += f23.x * w; a3 += f23.y * w;
        a4 += f45.x * w; a5 += f45.y * w; a6 += f67.x * w; a7 += f67.y * w;
    }
#pragma unroll
    for (int m = 8; m <= 32; m <<= 1) {
        a0 += __shfl_xor(a0, m); a1 += __shfl_xor(a1, m);
        a2 += __shfl_xor(a2, m); a3 += __shfl_xor(a3, m);
        a4 += __shfl_xor(a4, m); a5 += __shfl_xor(a5, m);
        a6 += __shfl_xor(a6, m); a7 += __shfl_xor(a7, m);
    }

    float dn = dinv[node];
    uint4 sv = *(const uint4*)(hp16 + (size_t)node * 64 + sub * 8);
    float2 s01 = __half22float2(*(const __half2*)&sv.x);
    float2 s23 = __half22float2(*(const __half2*)&sv.y);
    float2 s45 = __half22float2(*(const __half2*)&sv.z);
    float2 s67 = __half22float2(*(const __half2*)&sv.w);
    float4 bA = *(const float4*)(b + sub * 8);
    float4 bB = *(const float4*)(b + sub * 8 + 4);
    float dn2 = dn * dn;
    float4 rA, rB;
    rA.x = dn * a0 + dn2 * s01.x + bA.x;  rA.x = rA.x > 0.f ? rA.x : 0.f;
    rA.y = dn * a1 + dn2 * s01.y + bA.y;  rA.y = rA.y > 0.f ? rA.y : 0.f;
    rA.z = dn * a2 + dn2 * s23.x + bA.z;  rA.z = rA.z > 0.f ? rA.z : 0.f;
    rA.w = dn * a3 + dn2 * s23.y + bA.w;  rA.w = rA.w > 0.f ? rA.w : 0.f;
    rB.x = dn * a4 + dn2 * s45.x + bB.x;  rB.x = rB.x > 0.f ? rB.x : 0.f;
    rB.y = dn * a5 + dn2 * s45.y + bB.y;  rB.y = rB.y > 0.f ? rB.y : 0.f;
    rB.z = dn * a6 + dn2 * s67.x + bB.z;  rB.z = rB.z > 0.f ? rB.z : 0.f;
    rB.w = dn * a7 + dn2 * s67.y + bB.w;  rB.w = rB.w > 0.f ? rB.w : 0.f;
    if (g == 0) {
        *(float4*)(out + (size_t)node * 64 + sub * 8)     = rA;
        *(float4*)(out + (size_t)node * 64 + sub * 8 + 4) = rB;
    }
}

// ---------------- FUSED pooling + MLP + log_softmax: one block per graph ----------------
// Replaces pool_kernel + 3 memsets + mlp_kernel (5 dispatches -> 1). Each block
// binary-searches its graph's node range in the sorted batch array, register-
// accumulates sum/max over ~780 nodes (coalesced 768B/node across 192 threads),
// then runs the JK-cat MLP head in-block. Zero atomics, zero zero-init.
__global__ void pool_mlp_kernel(const float* __restrict__ h1, const float* __restrict__ h2,
                                const float* __restrict__ h3, const int* __restrict__ batch,
                                const float* __restrict__ lin1_W, const float* __restrict__ lin1_b,
                                const float* __restrict__ lin2_W, const float* __restrict__ lin2_b,
                                float* __restrict__ out, int n) {
    int g = blockIdx.x;                    // 64 blocks x 192 threads
    __shared__ int srange[2];
    __shared__ float gv[576];
    __shared__ float hid[64];
    int t = threadIdx.x;
    if (t < 2) {                           // lower_bound(batch, g + t)
        int key = g + t;
        int lo = 0, hi = n;
        while (lo < hi) { int m = (lo + hi) >> 1; if (batch[m] < key) lo = m + 1; else hi = m; }
        srange[t] = lo;
    }
    __syncthreads();
    int start = srange[0], end = srange[1];
    const float* src = (t < 64) ? h1 : ((t < 128) ? h2 : h3);
    int fo = t & 63;
    float sum = 0.f, mx = 0.f;             // post-ReLU features are >= 0
    for (int node = start; node < end; ++node) {
        float v = src[(size_t)node * 64 + fo];
        sum += v; mx = fmaxf(mx, v);
    }
    float cnt = (float)(end - start);
    gv[t] = sum;                           // add   [0..191]
    gv[192 + t] = sum / cnt;               // mean  [192..383]
    gv[384 + t] = mx;                      // max   [384..575]
    __syncthreads();
    if (t < 64) {
        float acc = lin1_b[t];
#pragma unroll 8
        for (int k = 0; k < 576; ++k) acc += gv[k] * lin1_W[k * 64 + t];
        hid[t] = acc > 0.f ? acc : 0.f;
    }
    __syncthreads();
    if (t == 0) {
        float l0 = lin2_b[0], l1 = lin2_b[1];
        for (int k = 0; k < 64; ++k) {
            l0 += hid[k] * lin2_W[k * 2 + 0];
            l1 += hid[k] * lin2_W[k * 2 + 1];
        }
        float m = fmaxf(l0, l1);
        float lse = m + logf(expf(l0 - m) + expf(l1 - m));
        out[g * 2 + 0] = l0 - lse;
        out[g * 2 + 1] = l1 - lse;
    }
}

extern "C" void kernel_launch(void* const* d_in, const int* in_sizes, int n_in,
                              void* d_out, int out_size, void* d_ws, size_t ws_size,
                              hipStream_t stream) {
    const float* x      = (const float*)d_in[0];
    const float* W1     = (const float*)d_in[1];
    const float* b1     = (const float*)d_in[2];
    const float* W2     = (const float*)d_in[3];
    const float* b2     = (const float*)d_in[4];
    const float* W3     = (const float*)d_in[5];
    const float* b3     = (const float*)d_in[6];
    const float* lin1_W = (const float*)d_in[7];
    const float* lin1_b = (const float*)d_in[8];
    const float* lin2_W = (const float*)d_in[9];
    const float* lin2_b = (const float*)d_in[10];
    const int*   ei     = (const int*)d_in[11];
    const int*   batch  = (const int*)d_in[12];
    float* out = (float*)d_out;

    char* ws = (char*)d_ws;
    size_t off = 0;
    auto alloc = [&](size_t bytes) {
        void* p = ws + off;
        off = (off + bytes + 255) & ~(size_t)255;
        return p;
    };
    int*   ideg    = (int*)  alloc(N_NODES * 4);
    float* dinv    = (float*)alloc(N_NODES * 4);
    int*   offs    = (int*)  alloc((N_NODES + 1) * 4);
    int*   cur     = (int*)  alloc(N_NODES * 4);
    int*   bsum    = (int*)  alloc(SCAN_B * 4);
    int*   bbase   = (int*)  alloc(SCAN_B * 4);
    unsigned int* csr = (unsigned int*)alloc((size_t)N_EDGES * 4);
    __half* hpA    = (__half*)alloc((size_t)N_NODES * 64 * 2);
    __half* hpB    = (__half*)alloc((size_t)N_NODES * 64 * 2);
    float* h1      = (float*)alloc((size_t)N_NODES * 64 * 4);
    float* h2      = (float*)alloc((size_t)N_NODES * 64 * 4);
    float* h3      = (float*)alloc((size_t)N_NODES * 64 * 4);

    // normalization + CSR offsets (fill fused with matmul1 below)
    hipMemsetAsync(ideg, 0, N_NODES * 4, stream);
    deg_kernel<<<(N_EDGES / 4 + 255) / 256, 256, 0, stream>>>(ei, ideg, N_EDGES);
    scan_part <<<SCAN_B, 256, 0, stream>>>(ideg, bsum, N_NODES);
    scan_base <<<1, 256, 0, stream>>>(bsum, bbase, SCAN_B);
    scan_final<<<SCAN_B, 256, 0, stream>>>(ideg, bbase, offs, cur, dinv, N_NODES);

    const int mmGrid  = (N_NODES + 15) / 16;     // 3125
    const int aggGrid = (N_NODES + 3) / 4;       // 12500 (one wave per node)

    // layer 1: fill + X@W1 -> hpA (fp16)
    fused_fill_mm1<<<FUSE_B, 256, 0, stream>>>(ei, dinv, cur, csr, x, W1, hpA, N_NODES, N_EDGES);
    agg_kernel<<<aggGrid, 256, 0, stream>>>(hpA, dinv, offs, csr, b1, h1, N_NODES);
    // layer 2
    matmul_kernel<HID><<<mmGrid, 256, 0, stream>>>(h1, W2, hpB, N_NODES);
    agg_kernel<<<aggGrid, 256, 0, stream>>>(hpB, dinv, offs, csr, b2, h2, N_NODES);
    // layer 3
    matmul_kernel<HID><<<mmGrid, 256, 0, stream>>>(h2, W3, hpA, N_NODES);
    agg_kernel<<<aggGrid, 256, 0, stream>>>(hpA, dinv, offs, csr, b3, h3, N_NODES);

    // fused pooling + head MLP + log_softmax (replaces pool + 3 memsets + mlp)
    pool_mlp_kernel<<<N_GRAPHS, 192, 0, stream>>>(h1, h2, h3, batch,
                                                  lin1_W, lin1_b, lin2_W, lin2_b, out, N_NODES);
}

// Round 16
// 352.111 us; speedup vs baseline: 1.4986x; 1.4986x over previous
//
#include <hip/hip_runtime.h>
#include <hip/hip_fp16.h>

#define N_NODES 50000
#define N_EDGES 800000
#define F_IN 128
#define HID 64
#define N_GRAPHS 64

#define SCAN_B ((N_NODES + 255) / 256)     // 196 blocks
#define FUSE_B ((N_EDGES + 255) / 256)     // 3125 blocks; == N_NODES/16 exactly

// ---------------- degree (int4-vectorized over contiguous dst row) ----------------
__global__ void deg_kernel(const int* __restrict__ ei, int* __restrict__ ideg, int E) {
    int i = blockIdx.x * blockDim.x + threadIdx.x;
    if (i * 4 >= E) return;
    int4 d = ((const int4*)(ei + E))[i];   // dst = ei[1][*], contiguous
    atomicAdd(&ideg[d.x], 1);
    atomicAdd(&ideg[d.y], 1);
    atomicAdd(&ideg[d.z], 1);
    atomicAdd(&ideg[d.w], 1);
}

// ---------------- 3-phase parallel exclusive scan of in-degrees (+ fused dinv) ----------------
__global__ void scan_part(const int* __restrict__ ideg, int* __restrict__ bsum, int n) {
    __shared__ int s[256];
    int t = threadIdx.x;
    int i = blockIdx.x * 256 + t;
    s[t] = (i < n) ? ideg[i] : 0;
    __syncthreads();
    for (int o = 128; o > 0; o >>= 1) {
        if (t < o) s[t] += s[t + o];
        __syncthreads();
    }
    if (t == 0) bsum[blockIdx.x] = s[0];
}

__global__ void scan_base(const int* __restrict__ bsum, int* __restrict__ bbase, int B) {
    __shared__ int s[256];
    int t = threadIdx.x;
    s[t] = (t < B) ? bsum[t] : 0;
    __syncthreads();
    for (int o = 1; o < 256; o <<= 1) {
        int v = (t >= o) ? s[t - o] : 0;
        __syncthreads();
        s[t] += v;
        __syncthreads();
    }
    if (t < B) bbase[t] = (t == 0) ? 0 : s[t - 1];
}

__global__ void scan_final(const int* __restrict__ ideg, const int* __restrict__ bbase,
                           int* __restrict__ offs, int* __restrict__ cur,
                           float* __restrict__ dinv, int n) {
    __shared__ int s[256];
    int t = threadIdx.x;
    int i = blockIdx.x * 256 + t;
    int v = (i < n) ? ideg[i] : 0;
    s[t] = v;
    __syncthreads();
    for (int o = 1; o < 256; o <<= 1) {
        int u = (t >= o) ? s[t - o] : 0;
        __syncthreads();
        s[t] += u;
        __syncthreads();
    }
    int excl = bbase[blockIdx.x] + s[t] - v;   // exclusive prefix
    if (i < n) {
        offs[i] = excl; cur[i] = excl;
        dinv[i] = rsqrtf((float)v + 1.0f);     // fused normalization coeff
    }
    if (i == n - 1) offs[n] = excl + v;        // total == E
}

// ---------------- FUSED (phased): every block fills 256 edges AND matmuls 16 nodes ----------------
// csr entry is 4B packed {w:fp16 hi16, src:u16 lo16} (N_NODES < 2^16).
__global__ void fused_fill_mm1(const int* __restrict__ ei, const float* __restrict__ dinv,
                               int* __restrict__ cur, unsigned int* __restrict__ csr,
                               const float* __restrict__ X, const float* __restrict__ W,
                               __half* __restrict__ Y16, int n, int E) {
    constexpr int F = F_IN;
    constexpr int S = F + 4;
    __shared__ float sWt[64 * S];          // [feat][k]
    __shared__ float sX[16 * F];           // [node][k]
    int tid = threadIdx.x;

    // ---- phase 1: fill front-end (atomic issued now, store deferred) ----
    int e = blockIdx.x * 256 + tid;
    unsigned int pk = 0; int pos = -1;
    if (e < E) {
        int esrc = ei[e];
        int d = ei[E + e];
        __half hw = __float2half(dinv[esrc]);
        pk = ((unsigned int)(*(unsigned short*)&hw) << 16) | (unsigned int)(esrc & 0xFFFF);
        pos = atomicAdd(&cur[d], 1);
    }

    // ---- phase 2: matmul Y[16 nodes, 64] = X @ W ----
    for (int j = tid; j < F * 64; j += 256) {
        int k = j >> 6, f = j & 63;        // W is [k][f] row-major
        sWt[f * S + k] = W[j];
    }
    int nodeBase = blockIdx.x * 16;
    for (int i = tid; i < 16 * F; i += 256) {
        int node = nodeBase + i / F;
        sX[i] = (node < n) ? X[(size_t)node * F + (i % F)] : 0.0f;
    }
    __syncthreads();
    int feat = tid & 63;
    int q = tid >> 6;                      // wave id: nodes q*4 .. q*4+3
    const float4* wt = (const float4*)&sWt[feat * S];
    const float4* x0 = (const float4*)&sX[(q * 4 + 0) * F];
    const float4* x1 = (const float4*)&sX[(q * 4 + 1) * F];
    const float4* x2 = (const float4*)&sX[(q * 4 + 2) * F];
    const float4* x3 = (const float4*)&sX[(q * 4 + 3) * F];
    float a0 = 0.f, a1 = 0.f, a2 = 0.f, a3 = 0.f;
#pragma unroll 8
    for (int k4 = 0; k4 < F / 4; ++k4) {
        float4 w = wt[k4];
        float4 v;
        v = x0[k4]; a0 += v.x * w.x + v.y * w.y + v.z * w.z + v.w * w.w;
        v = x1[k4]; a1 += v.x * w.x + v.y * w.y + v.z * w.z + v.w * w.w;
        v = x2[k4]; a2 += v.x * w.x + v.y * w.y + v.z * w.z + v.w * w.w;
        v = x3[k4]; a3 += v.x * w.x + v.y * w.y + v.z * w.z + v.w * w.w;
    }
    int n0 = nodeBase + q * 4;
    if (n0 + 0 < n) Y16[(size_t)(n0 + 0) * 64 + feat] = __float2half(a0);
    if (n0 + 1 < n) Y16[(size_t)(n0 + 1) * 64 + feat] = __float2half(a1);
    if (n0 + 2 < n) Y16[(size_t)(n0 + 2) * 64 + feat] = __float2half(a2);
    if (n0 + 3 < n) Y16[(size_t)(n0 + 3) * 64 + feat] = __float2half(a3);

    // ---- phase 3: deferred CSR store (4B packed) ----
    if (pos >= 0) csr[pos] = pk;
}

// ---------------- dense matmul (layers 2,3): h fp32 in -> hp16 out ----------------
template <int F>
__global__ void matmul_kernel(const float* __restrict__ X, const float* __restrict__ W,
                              __half* __restrict__ Y16, int n) {
    constexpr int S = F + 4;
    __shared__ float sWt[64 * S];
    __shared__ float sX[16 * F];
    int tid = threadIdx.x;
    for (int j = tid; j < F * 64; j += 256) {
        int k = j >> 6, f = j & 63;
        sWt[f * S + k] = W[j];
    }
    int nodeBase = blockIdx.x * 16;
    for (int i = tid; i < 16 * F; i += 256) {
        int node = nodeBase + i / F;
        sX[i] = (node < n) ? X[(size_t)node * F + (i % F)] : 0.0f;
    }
    __syncthreads();
    int feat = tid & 63;
    int q = tid >> 6;
    const float4* wt = (const float4*)&sWt[feat * S];
    const float4* x0 = (const float4*)&sX[(q * 4 + 0) * F];
    const float4* x1 = (const float4*)&sX[(q * 4 + 1) * F];
    const float4* x2 = (const float4*)&sX[(q * 4 + 2) * F];
    const float4* x3 = (const float4*)&sX[(q * 4 + 3) * F];
    float a0 = 0.f, a1 = 0.f, a2 = 0.f, a3 = 0.f;
#pragma unroll 8
    for (int k4 = 0; k4 < F / 4; ++k4) {
        float4 w = wt[k4];
        float4 v;
        v = x0[k4]; a0 += v.x * w.x + v.y * w.y + v.z * w.z + v.w * w.w;
        v = x1[k4]; a1 += v.x * w.x + v.y * w.y + v.z * w.z + v.w * w.w;
        v = x2[k4]; a2 += v.x * w.x + v.y * w.y + v.z * w.z + v.w * w.w;
        v = x3[k4]; a3 += v.x * w.x + v.y * w.y + v.z * w.z + v.w * w.w;
    }
    int n0 = nodeBase + q * 4;
    if (n0 + 0 < n) Y16[(size_t)(n0 + 0) * 64 + feat] = __float2half(a0);
    if (n0 + 1 < n) Y16[(size_t)(n0 + 1) * 64 + feat] = __float2half(a1);
    if (n0 + 2 < n) Y16[(size_t)(n0 + 2) * 64 + feat] = __float2half(a2);
    if (n0 + 3 < n) Y16[(size_t)(n0 + 3) * 64 + feat] = __float2half(a3);
}

// ---------------- agg v4: 8 row-gathers per dwordx4 VMEM instruction ----------------
// One wave per node. Wave = 8 groups x 8 lanes; group g handles edge i+g, lane sub
// loads uint4 (16B) -> 8 lanes x 16B = the full 128B fp16 row in ONE instruction
// covering 8 distinct rows. Per 8 edges: 2 VMEM instructions. At the L2 line-service
// wall (~16 cyc/line); keep LEAN (R8/R11/R12: attached work regresses).
__global__ void agg_kernel(const __half* __restrict__ hp16, const float* __restrict__ dinv,
                           const int* __restrict__ offs, const unsigned int* __restrict__ csr,
                           const float* __restrict__ b, float* __restrict__ out, int n) {
    int node = blockIdx.x * 4 + (threadIdx.x >> 6);
    if (node >= n) return;
    int lane = threadIdx.x & 63;
    int g = lane >> 3;                     // edge-group 0..7
    int sub = lane & 7;                    // feature octet (feats 8*sub..8*sub+7)
    int beg = offs[node], end = offs[node + 1];

    float a0 = 0.f, a1 = 0.f, a2 = 0.f, a3 = 0.f;
    float a4 = 0.f, a5 = 0.f, a6 = 0.f, a7 = 0.f;
#pragma unroll 2
    for (int i = beg; i < end; i += 8) {
        int idx = i + g;
        unsigned int pk = csr[min(idx, end - 1)];
        int src = (int)(pk & 0xFFFFu);
        __half_raw hr; hr.x = (unsigned short)(pk >> 16);
        float w = (idx < end) ? __half2float(*(__half*)&hr) : 0.f;
        uint4 hv = *(const uint4*)(hp16 + (size_t)src * 64 + sub * 8);
        float2 f01 = __half22float2(*(const __half2*)&hv.x);
        float2 f23 = __half22float2(*(const __half2*)&hv.y);
        float2 f45 = __half22float2(*(const __half2*)&hv.z);
        float2 f67 = __half22float2(*(const __half2*)&hv.w);
        a0 += f01.x * w; a1 += f01.y * w; a2 += f23.x * w; a3 += f23.y * w;
        a4 += f45.x * w; a5 += f45.y * w; a6 += f67.x * w; a7 += f67.y * w;
    }
#pragma unroll
    for (int m = 8; m <= 32; m <<= 1) {
        a0 += __shfl_xor(a0, m); a1 += __shfl_xor(a1, m);
        a2 += __shfl_xor(a2, m); a3 += __shfl_xor(a3, m);
        a4 += __shfl_xor(a4, m); a5 += __shfl_xor(a5, m);
        a6 += __shfl_xor(a6, m); a7 += __shfl_xor(a7, m);
    }

    float dn = dinv[node];
    uint4 sv = *(const uint4*)(hp16 + (size_t)node * 64 + sub * 8);
    float2 s01 = __half22float2(*(const __half2*)&sv.x);
    float2 s23 = __half22float2(*(const __half2*)&sv.y);
    float2 s45 = __half22float2(*(const __half2*)&sv.z);
    float2 s67 = __half22float2(*(const __half2*)&sv.w);
    float4 bA = *(const float4*)(b + sub * 8);
    float4 bB = *(const float4*)(b + sub * 8 + 4);
    float dn2 = dn * dn;
    float4 rA, rB;
    rA.x = dn * a0 + dn2 * s01.x + bA.x;  rA.x = rA.x > 0.f ? rA.x : 0.f;
    rA.y = dn * a1 + dn2 * s01.y + bA.y;  rA.y = rA.y > 0.f ? rA.y : 0.f;
    rA.z = dn * a2 + dn2 * s23.x + bA.z;  rA.z = rA.z > 0.f ? rA.z : 0.f;
    rA.w = dn * a3 + dn2 * s23.y + bA.w;  rA.w = rA.w > 0.f ? rA.w : 0.f;
    rB.x = dn * a4 + dn2 * s45.x + bB.x;  rB.x = rB.x > 0.f ? rB.x : 0.f;
    rB.y = dn * a5 + dn2 * s45.y + bB.y;  rB.y = rB.y > 0.f ? rB.y : 0.f;
    rB.z = dn * a6 + dn2 * s67.x + bB.z;  rB.z = rB.z > 0.f ? rB.z : 0.f;
    rB.w = dn * a7 + dn2 * s67.y + bB.w;  rB.w = rB.w > 0.f ? rB.w : 0.f;
    if (g == 0) {
        *(float4*)(out + (size_t)node * 64 + sub * 8)     = rA;
        *(float4*)(out + (size_t)node * 64 + sub * 8 + 4) = rB;
    }
}

// ---------------- pooling over sorted batch: sum / count / max ----------------
// 512 blocks x 192 threads (R15 lesson: one-block-per-graph collapses occupancy).
__global__ void pool_kernel(const float* __restrict__ h1, const float* __restrict__ h2,
                            const float* __restrict__ h3, const int* __restrict__ batch,
                            float* __restrict__ padd, unsigned int* __restrict__ pmax,
                            int* __restrict__ pcnt, int n, int chunk) {
    int f = threadIdx.x;                       // 0..191
    int start = blockIdx.x * chunk;
    int end = min(start + chunk, n);
    if (start >= end) return;
    const float* src = (f < 64) ? h1 : ((f < 128) ? h2 : h3);
    int fo = f & 63;
    float sum = 0.0f, mx = 0.0f;               // features are post-ReLU (>=0)
    int g = batch[start];
    int runStart = start;
    for (int node = start; node < end; ++node) {
        int bg = batch[node];
        if (bg != g) {
            unsafeAtomicAdd(&padd[g * 192 + f], sum);
            atomicMax(&pmax[g * 192 + f], __float_as_uint(mx));
            if (f == 0) atomicAdd(&pcnt[g], node - runStart);
            sum = 0.0f; mx = 0.0f; g = bg; runStart = node;
        }
        float v = src[(size_t)node * 64 + fo];
        sum += v;
        mx = fmaxf(mx, v);
    }
    unsafeAtomicAdd(&padd[g * 192 + f], sum);
    atomicMax(&pmax[g * 192 + f], __float_as_uint(mx));
    if (f == 0) atomicAdd(&pcnt[g], end - runStart);
}

// ---------------- per-graph MLP + log_softmax ----------------
__global__ void mlp_kernel(const float* __restrict__ padd, const unsigned int* __restrict__ pmax,
                           const int* __restrict__ pcnt,
                           const float* __restrict__ lin1_W, const float* __restrict__ lin1_b,
                           const float* __restrict__ lin2_W, const float* __restrict__ lin2_b,
                           float* __restrict__ out) {
    int g = blockIdx.x;     // 64 blocks x 64 threads
    int t = threadIdx.x;
    __shared__ float gv[576];
    __shared__ float hid[64];
    float cnt = (float)pcnt[g];
    for (int i = t; i < 192; i += 64) {
        float a = padd[g * 192 + i];
        gv[i] = a;                                   // add
        gv[192 + i] = a / cnt;                       // mean
        gv[384 + i] = __uint_as_float(pmax[g * 192 + i]);  // max
    }
    __syncthreads();
    float acc = lin1_b[t];
#pragma unroll 8
    for (int k = 0; k < 576; ++k) acc += gv[k] * lin1_W[k * 64 + t];
    hid[t] = acc > 0.0f ? acc : 0.0f;
    __syncthreads();
    if (t == 0) {
        float l0 = lin2_b[0], l1 = lin2_b[1];
        for (int k = 0; k < 64; ++k) {
            l0 += hid[k] * lin2_W[k * 2 + 0];
            l1 += hid[k] * lin2_W[k * 2 + 1];
        }
        float m = fmaxf(l0, l1);
        float lse = m + logf(expf(l0 - m) + expf(l1 - m));
        out[g * 2 + 0] = l0 - lse;
        out[g * 2 + 1] = l1 - lse;
    }
}

extern "C" void kernel_launch(void* const* d_in, const int* in_sizes, int n_in,
                              void* d_out, int out_size, void* d_ws, size_t ws_size,
                              hipStream_t stream) {
    const float* x      = (const float*)d_in[0];
    const float* W1     = (const float*)d_in[1];
    const float* b1     = (const float*)d_in[2];
    const float* W2     = (const float*)d_in[3];
    const float* b2     = (const float*)d_in[4];
    const float* W3     = (const float*)d_in[5];
    const float* b3     = (const float*)d_in[6];
    const float* lin1_W = (const float*)d_in[7];
    const float* lin1_b = (const float*)d_in[8];
    const float* lin2_W = (const float*)d_in[9];
    const float* lin2_b = (const float*)d_in[10];
    const int*   ei     = (const int*)d_in[11];
    const int*   batch  = (const int*)d_in[12];
    float* out = (float*)d_out;

    char* ws = (char*)d_ws;
    size_t off = 0;
    auto alloc = [&](size_t bytes) {
        void* p = ws + off;
        off = (off + bytes + 255) & ~(size_t)255;
        return p;
    };
    int*   ideg    = (int*)  alloc(N_NODES * 4);
    float* dinv    = (float*)alloc(N_NODES * 4);
    int*   offs    = (int*)  alloc((N_NODES + 1) * 4);
    int*   cur     = (int*)  alloc(N_NODES * 4);
    int*   bsum    = (int*)  alloc(SCAN_B * 4);
    int*   bbase   = (int*)  alloc(SCAN_B * 4);
    unsigned int* csr = (unsigned int*)alloc((size_t)N_EDGES * 4);
    __half* hpA    = (__half*)alloc((size_t)N_NODES * 64 * 2);
    __half* hpB    = (__half*)alloc((size_t)N_NODES * 64 * 2);
    float* h1      = (float*)alloc((size_t)N_NODES * 64 * 4);
    float* h2      = (float*)alloc((size_t)N_NODES * 64 * 4);
    float* h3      = (float*)alloc((size_t)N_NODES * 64 * 4);
    float* padd    = (float*)alloc(N_GRAPHS * 192 * 4);
    unsigned int* pmax = (unsigned int*)alloc(N_GRAPHS * 192 * 4);
    int*   pcnt    = (int*) alloc(N_GRAPHS * 4);

    // normalization + CSR offsets (fill fused with matmul1 below)
    hipMemsetAsync(ideg, 0, N_NODES * 4, stream);
    deg_kernel<<<(N_EDGES / 4 + 255) / 256, 256, 0, stream>>>(ei, ideg, N_EDGES);
    scan_part <<<SCAN_B, 256, 0, stream>>>(ideg, bsum, N_NODES);
    scan_base <<<1, 256, 0, stream>>>(bsum, bbase, SCAN_B);
    scan_final<<<SCAN_B, 256, 0, stream>>>(ideg, bbase, offs, cur, dinv, N_NODES);

    const int mmGrid  = (N_NODES + 15) / 16;     // 3125
    const int aggGrid = (N_NODES + 3) / 4;       // 12500 (one wave per node)

    // layer 1: fill + X@W1 -> hpA (fp16)
    fused_fill_mm1<<<FUSE_B, 256, 0, stream>>>(ei, dinv, cur, csr, x, W1, hpA, N_NODES, N_EDGES);
    agg_kernel<<<aggGrid, 256, 0, stream>>>(hpA, dinv, offs, csr, b1, h1, N_NODES);
    // layer 2
    matmul_kernel<HID><<<mmGrid, 256, 0, stream>>>(h1, W2, hpB, N_NODES);
    agg_kernel<<<aggGrid, 256, 0, stream>>>(hpB, dinv, offs, csr, b2, h2, N_NODES);
    // layer 3
    matmul_kernel<HID><<<mmGrid, 256, 0, stream>>>(h2, W3, hpA, N_NODES);
    agg_kernel<<<aggGrid, 256, 0, stream>>>(hpA, dinv, offs, csr, b3, h3, N_NODES);

    // pooling
    hipMemsetAsync(padd, 0, N_GRAPHS * 192 * 4, stream);
    hipMemsetAsync(pmax, 0, N_GRAPHS * 192 * 4, stream);
    hipMemsetAsync(pcnt, 0, N_GRAPHS * 4, stream);
    const int chunk = (N_NODES + 511) / 512;           // 98 nodes/block
    pool_kernel<<<512, 192, 0, stream>>>(h1, h2, h3, batch, padd, pmax, pcnt, N_NODES, chunk);

    // head MLP + log_softmax
    mlp_kernel<<<N_GRAPHS, 64, 0, stream>>>(padd, pmax, pcnt, lin1_W, lin1_b, lin2_W, lin2_b, out);
}